// Round 9
// baseline (8930.082 us; speedup 1.0000x reference)
//
#include <hip/hip_runtime.h>

#define SEQ 512
#define BB 64
#define IN_DIM 128
#define HH 256
#define NL 6
#define G3 768
#define GPL 4            // batch-groups per layer
#define MB 16            // batches per group
#define CHUNK 8
#define NSLOT 4
#define NCH (SEQ/CHUNK)  // 64

typedef short short8 __attribute__((ext_vector_type(8)));
typedef float f32x4 __attribute__((ext_vector_type(4)));

#define L0_F (4*48)                    // layer0 W_ih frags (KT=4)
#define LN_F (8*48)                    // layers1-5 (KT=8)
#define TOT_F (L0_F + 5*LN_F)          // 2112
#define STREAM_SH ((size_t)TOT_F*512)
#define FR_SLOT 32768                  // shorts per fring chunk-slot (8*16*256)
#define FRING_SH ((size_t)5*GPL*NSLOT*FR_SLOT)
#define XG_OFF_B ((STREAM_SH + FRING_SH)*2)
#define XG_CU_FLOATS ((size_t)CHUNK*G3*MB)          // 98304 per CU
#define FLAGS_OFF_B (XG_OFF_B + (size_t)NL*GPL*XG_CU_FLOATS*4)
#define NFLAG_INTS (16 + 2*NL*GPL*16)

__device__ __forceinline__ short f2bf(float f) {
    unsigned u = __builtin_bit_cast(unsigned, f);
    u += 0x7fffu + ((u >> 16) & 1u);   // RNE
    return (short)(u >> 16);
}
__device__ __forceinline__ float sigm(float v) { return __fdividef(1.f, 1.f + __expf(-v)); }
__device__ __forceinline__ float tanh_f(float v) { float e = __expf(2.f * v); return 1.f - __fdividef(2.f, e + 1.f); }

__device__ __forceinline__ void spin1(int* p, int target, unsigned long long ddl) {
    if (__hip_atomic_load(p, __ATOMIC_RELAXED, __HIP_MEMORY_SCOPE_AGENT) >= target) return;
    for (;;) {
        __builtin_amdgcn_s_sleep(2);
        if (__hip_atomic_load(p, __ATOMIC_RELAXED, __HIP_MEMORY_SCOPE_AGENT) >= target) return;
        if (__builtin_amdgcn_s_memrealtime() > ddl) return;   // fail-visible
    }
}

struct F4x4 { f32x4 a, b, c, d; };
// 4 x f32x4 L1-bypassing loads, one wait (own-L2 fresh data)
__device__ __forceinline__ F4x4 ld4x4_sc0(const float* p0, const float* p1,
                                          const float* p2, const float* p3) {
    F4x4 r;
    asm volatile(
        "global_load_dwordx4 %0, %4, off sc0\n\t"
        "global_load_dwordx4 %1, %5, off sc0\n\t"
        "global_load_dwordx4 %2, %6, off sc0\n\t"
        "global_load_dwordx4 %3, %7, off sc0\n\t"
        "s_waitcnt vmcnt(0)"
        : "=&v"(r.a), "=&v"(r.b), "=&v"(r.c), "=&v"(r.d)
        : "v"(p0), "v"(p1), "v"(p2), "v"(p3) : "memory");
    return r;
}

// ---- prep: W_ih fp32 -> bf16 MFMA B-fragment stream (frag = 1KB, coalesced) ----
__global__ __launch_bounds__(256) void prep_frags(
    const float* __restrict__ w_ih0, const float* __restrict__ w_ih_rest,
    short* __restrict__ stream)
{
    int id = blockIdx.x * 256 + threadIdx.x;
    if (id >= TOT_F * 64) return;
    int fid = id >> 6, lane = id & 63;
    int l, rem;
    if (fid < L0_F) { l = 0; rem = fid; }
    else { int z = fid - L0_F; l = 1 + z / LN_F; rem = z % LN_F; }
    int kt = rem / 48, nt = rem % 48;
    int gt = nt >> 4, jt = nt & 15;
    int jj = lane & 15, q2 = lane >> 4;
    int row = gt * 256 + jt * 16 + jj;
    int k0 = kt * 32 + q2 * 8;
    const float* src = (l == 0) ? (w_ih0 + (size_t)row * IN_DIM + k0)
                                : (w_ih_rest + (size_t)(l - 1) * G3 * HH + (size_t)row * HH + k0);
    float4 a = *(const float4*)src;
    float4 c = *(const float4*)(src + 4);
    short8 v;
    v[0] = f2bf(a.x); v[1] = f2bf(a.y); v[2] = f2bf(a.z); v[3] = f2bf(a.w);
    v[4] = f2bf(c.x); v[5] = f2bf(c.y); v[6] = f2bf(c.z); v[7] = f2bf(c.w);
    *((short8*)stream + (size_t)fid * 64 + lane) = v;
}

__global__ __launch_bounds__(256, 1) void gru_persist(
    const float* __restrict__ x, const float* __restrict__ h0,
    const float* __restrict__ w_hh, const float* __restrict__ b_ih,
    const float* __restrict__ b_hh, float* __restrict__ y,
    const short* __restrict__ wstream, short* __restrict__ fring,
    float* __restrict__ xg, int* __restrict__ flags)
{
    const int tid = threadIdx.x;
    const unsigned long long ddl = __builtin_amdgcn_s_memrealtime() + 1000000000ull; // ~10s

    const int xcc = __builtin_amdgcn_s_getreg(20 | (31 << 11)) & 0xf;  // HW_REG_XCC_ID
    if (xcc >= NL) return;
    __shared__ int s_slot;
    if (tid == 0) s_slot = __hip_atomic_fetch_add(&flags[xcc], 1, __ATOMIC_RELAXED, __HIP_MEMORY_SCOPE_AGENT);
    __syncthreads();
    const int g = s_slot;
    if (g >= GPL) return;

    const int l = xcc;
    const int lane = tid & 63;
    const int wave = tid >> 6;       // 4 waves; wave owns j in [64w, 64w+64)
    const int q = lane >> 4;
    const int jj = lane & 15;

    int* seqf      = flags + 16 + (l * GPL + g) * 16;
    int* cseqf     = flags + 16 + NL * GPL * 16 + (l * GPL + g) * 16;
    int* seq_prev  = flags + 16 + ((l - 1) * GPL + g) * 16;
    int* cseq_next = flags + 16 + NL * GPL * 16 + ((l + 1) * GPL + g) * 16;

    __shared__ short sW[16 * 16 * 256];   // n-gate W_hh tiles, XOR-swizzled (131072 B)
    __shared__ short sHl[16 * 256];       // h(t-1) bf16, XOR-swizzled (8192 B)

    // ---- resident W_hh: tt 0..7 (r,z) in regs; tt 8..11 (n) in LDS ----
    const float* whh = w_hh + (size_t)l * G3 * HH;
    short8 Wreg[8][8];
    #pragma unroll
    for (int tt = 0; tt < 8; ++tt) {
        int row = (tt >> 2) * 256 + (4 * wave + (tt & 3)) * 16 + jj;
        #pragma unroll
        for (int kt = 0; kt < 8; ++kt) {
            const float* p = whh + (size_t)row * HH + kt * 32 + q * 8;
            float4 a = *(const float4*)p;
            float4 c = *(const float4*)(p + 4);
            short8 v;
            v[0] = f2bf(a.x); v[1] = f2bf(a.y); v[2] = f2bf(a.z); v[3] = f2bf(a.w);
            v[4] = f2bf(c.x); v[5] = f2bf(c.y); v[6] = f2bf(c.z); v[7] = f2bf(c.w);
            Wreg[tt][kt] = v;
        }
    }
    #pragma unroll
    for (int tb = 0; tb < 4; ++tb) {
        int row = 512 + (4 * wave + tb) * 16 + jj;
        #pragma unroll
        for (int kt = 0; kt < 8; ++kt) {
            const float* p = whh + (size_t)row * HH + kt * 32 + q * 8;
            float4 a = *(const float4*)p;
            float4 c = *(const float4*)(p + 4);
            short8 v;
            v[0] = f2bf(a.x); v[1] = f2bf(a.y); v[2] = f2bf(a.z); v[3] = f2bf(a.w);
            v[4] = f2bf(c.x); v[5] = f2bf(c.y); v[6] = f2bf(c.z); v[7] = f2bf(c.w);
            int kbyte = kt * 64 + q * 16;
            *(short8*)((char*)sW + (wave * 4 + tb) * 8192 + jj * 512 + (kbyte ^ ((jj & 7) << 4))) = v;
        }
    }

    // biases
    float biasv[12], bhn[4];
    #pragma unroll
    for (int tt = 0; tt < 12; ++tt) {
        int gt = tt >> 2;
        int j = (4 * wave + (tt & 3)) * 16 + jj;
        biasv[tt] = (gt < 2) ? (b_ih[l * G3 + gt * 256 + j] + b_hh[l * G3 + gt * 256 + j])
                             : b_ih[l * G3 + 512 + j];
    }
    #pragma unroll
    for (int jt2 = 0; jt2 < 4; ++jt2)
        bhn[jt2] = b_hh[l * G3 + 512 + (4 * wave + jt2) * 16 + jj];

    // ---- h0: fp32 regs + bf16 swizzled LDS ----
    float hcur[16];
    #pragma unroll
    for (int jt2 = 0; jt2 < 4; ++jt2) {
        int j = (4 * wave + jt2) * 16 + jj;
        #pragma unroll
        for (int r = 0; r < 4; ++r)
            hcur[jt2 * 4 + r] = h0[((size_t)l * BB + g * MB + 4 * q + r) * HH + j];
    }
    for (int i = tid; i < MB * HH; i += 256) {
        int b = i >> 8, j = i & 255;
        short hb = f2bf(h0[((size_t)l * BB + g * MB + b) * HH + j]);
        *(short*)((char*)sHl + b * 512 + ((2 * j) ^ ((b & 7) << 4))) = hb;
    }
    __syncthreads();

    const size_t lbase = (l == 0) ? 0 : (L0_F + (size_t)(l - 1) * LN_F);
    const int KTp = (l == 0) ? 4 : 8;
    float* xg_cu = xg + (size_t)(l * GPL + g) * XG_CU_FLOATS;

    for (int c = 0; c < NCH; ++c) {
        const int t0 = c * CHUNK;

        // ---- chunk sync (R8-proven) ----
        if (tid == 0) {
            if (l > 0) spin1(seq_prev, t0 + CHUNK, ddl);
            if (l < NL - 1 && c >= NSLOT) spin1(cseq_next, t0 - (NSLOT - 1) * CHUNK, ddl);
        }
        if (wave == 0) __builtin_amdgcn_fence(__ATOMIC_ACQUIRE, "agent");
        __syncthreads();

        const short* frsrc = (l > 0)
            ? fring + (((size_t)(l - 1) * GPL + g) * NSLOT + (c & 3)) * FR_SLOT : nullptr;

        // ---- proj: xg[t0..t0+7] = W_ih * input + bias ----
        for (int mh = 0; mh < 2; ++mh) {
            // pass A: r,z (tt 0..7)
            {
                f32x4 pa[8][4];
                #pragma unroll
                for (int tt = 0; tt < 8; ++tt)
                    #pragma unroll
                    for (int m4 = 0; m4 < 4; ++m4)
                        pa[tt][m4] = (f32x4){biasv[tt], biasv[tt], biasv[tt], biasv[tt]};
                for (int kt = 0; kt < KTp; ++kt) {
                    short8 af[4];
                    #pragma unroll
                    for (int m4 = 0; m4 < 4; ++m4) {
                        int ts = mh * 4 + m4;
                        if (l == 0) {
                            const float* ap = x + (((size_t)(t0 + ts) * BB + g * MB + jj) * IN_DIM + kt * 32 + q * 8);
                            float4 a1 = *(const float4*)ap;
                            float4 a2 = *(const float4*)(ap + 4);
                            short8 v;
                            v[0] = f2bf(a1.x); v[1] = f2bf(a1.y); v[2] = f2bf(a1.z); v[3] = f2bf(a1.w);
                            v[4] = f2bf(a2.x); v[5] = f2bf(a2.y); v[6] = f2bf(a2.z); v[7] = f2bf(a2.w);
                            af[m4] = v;
                        } else {
                            af[m4] = *(const short8*)(frsrc + (size_t)(ts * MB + jj) * HH + kt * 32 + q * 8);
                        }
                    }
                    #pragma unroll
                    for (int tt = 0; tt < 8; ++tt) {
                        int gt = tt >> 2, jt = 4 * wave + (tt & 3);
                        short8 bf = *((const short8*)wstream + ((lbase + kt * 48 + gt * 16 + jt) * 64 + lane));
                        #pragma unroll
                        for (int m4 = 0; m4 < 4; ++m4)
                            pa[tt][m4] = __builtin_amdgcn_mfma_f32_16x16x32_bf16(af[m4], bf, pa[tt][m4], 0, 0, 0);
                    }
                }
                #pragma unroll
                for (int tt = 0; tt < 8; ++tt) {
                    int gt = tt >> 2, jt = 4 * wave + (tt & 3);
                    #pragma unroll
                    for (int m4 = 0; m4 < 4; ++m4) {
                        int ts = mh * 4 + m4;
                        *(f32x4*)(xg_cu + ((size_t)ts * G3 + gt * 256 + jt * 16 + jj) * MB + 4 * q) = pa[tt][m4];
                    }
                }
            }
            // pass B: n (tt 8..11)
            {
                f32x4 pb[4][4];
                #pragma unroll
                for (int tb = 0; tb < 4; ++tb)
                    #pragma unroll
                    for (int m4 = 0; m4 < 4; ++m4)
                        pb[tb][m4] = (f32x4){biasv[8 + tb], biasv[8 + tb], biasv[8 + tb], biasv[8 + tb]};
                for (int kt = 0; kt < KTp; ++kt) {
                    short8 af[4];
                    #pragma unroll
                    for (int m4 = 0; m4 < 4; ++m4) {
                        int ts = mh * 4 + m4;
                        if (l == 0) {
                            const float* ap = x + (((size_t)(t0 + ts) * BB + g * MB + jj) * IN_DIM + kt * 32 + q * 8);
                            float4 a1 = *(const float4*)ap;
                            float4 a2 = *(const float4*)(ap + 4);
                            short8 v;
                            v[0] = f2bf(a1.x); v[1] = f2bf(a1.y); v[2] = f2bf(a1.z); v[3] = f2bf(a1.w);
                            v[4] = f2bf(a2.x); v[5] = f2bf(a2.y); v[6] = f2bf(a2.z); v[7] = f2bf(a2.w);
                            af[m4] = v;
                        } else {
                            af[m4] = *(const short8*)(frsrc + (size_t)(ts * MB + jj) * HH + kt * 32 + q * 8);
                        }
                    }
                    #pragma unroll
                    for (int tb = 0; tb < 4; ++tb) {
                        int jt = 4 * wave + tb;
                        short8 bf = *((const short8*)wstream + ((lbase + kt * 48 + 2 * 16 + jt) * 64 + lane));
                        #pragma unroll
                        for (int m4 = 0; m4 < 4; ++m4)
                            pb[tb][m4] = __builtin_amdgcn_mfma_f32_16x16x32_bf16(af[m4], bf, pb[tb][m4], 0, 0, 0);
                    }
                }
                #pragma unroll
                for (int tb = 0; tb < 4; ++tb) {
                    int jt = 4 * wave + tb;
                    #pragma unroll
                    for (int m4 = 0; m4 < 4; ++m4) {
                        int ts = mh * 4 + m4;
                        *(f32x4*)(xg_cu + ((size_t)ts * G3 + 512 + jt * 16 + jj) * MB + 4 * q) = pb[tb][m4];
                    }
                }
            }
        }
        __syncthreads();   // drain proj xg stores (vmcnt 0) before rec sc0 reads

        // ---- rec: 8 serial steps, W_hh resident ----
        short* frdst = (l < NL - 1)
            ? fring + (((size_t)l * GPL + g) * NSLOT + (c & 3)) * FR_SLOT : nullptr;
        for (int ts = 0; ts < CHUNK; ++ts) {
            const int jb = 4 * wave * 16 + jj;
            const float* xr = xg_cu + (size_t)ts * G3 * MB;
            F4x4 xrv = ld4x4_sc0(xr + (size_t)(jb) * MB + 4 * q,
                                 xr + (size_t)(jb + 16) * MB + 4 * q,
                                 xr + (size_t)(jb + 32) * MB + 4 * q,
                                 xr + (size_t)(jb + 48) * MB + 4 * q);
            F4x4 xzv = ld4x4_sc0(xr + (size_t)(256 + jb) * MB + 4 * q,
                                 xr + (size_t)(256 + jb + 16) * MB + 4 * q,
                                 xr + (size_t)(256 + jb + 32) * MB + 4 * q,
                                 xr + (size_t)(256 + jb + 48) * MB + 4 * q);
            F4x4 xnv = ld4x4_sc0(xr + (size_t)(512 + jb) * MB + 4 * q,
                                 xr + (size_t)(512 + jb + 16) * MB + 4 * q,
                                 xr + (size_t)(512 + jb + 32) * MB + 4 * q,
                                 xr + (size_t)(512 + jb + 48) * MB + 4 * q);
            f32x4 acc[12];
            acc[0] = xrv.a; acc[1] = xrv.b; acc[2] = xrv.c; acc[3] = xrv.d;
            acc[4] = xzv.a; acc[5] = xzv.b; acc[6] = xzv.c; acc[7] = xzv.d;
            acc[8] = (f32x4){0,0,0,0}; acc[9] = (f32x4){0,0,0,0};
            acc[10] = (f32x4){0,0,0,0}; acc[11] = (f32x4){0,0,0,0};

            #pragma unroll
            for (int kt = 0; kt < 8; ++kt) {
                int kbyte = kt * 64 + q * 16;
                int swz = kbyte ^ ((jj & 7) << 4);
                short8 af = *(const short8*)((const char*)sHl + jj * 512 + swz);
                #pragma unroll
                for (int tt = 0; tt < 8; ++tt)
                    acc[tt] = __builtin_amdgcn_mfma_f32_16x16x32_bf16(af, Wreg[tt][kt], acc[tt], 0, 0, 0);
                #pragma unroll
                for (int tb = 0; tb < 4; ++tb) {
                    short8 bf = *(const short8*)((const char*)sW + (wave * 4 + tb) * 8192 + jj * 512 + swz);
                    acc[8 + tb] = __builtin_amdgcn_mfma_f32_16x16x32_bf16(af, bf, acc[8 + tb], 0, 0, 0);
                }
            }
            __syncthreads();   // all sHl reads done before overwrite

            f32x4 xn4[4] = {xnv.a, xnv.b, xnv.c, xnv.d};
            float* ydst = y + (size_t)(t0 + ts) * BB * HH;
            #pragma unroll
            for (int jt2 = 0; jt2 < 4; ++jt2) {
                int j = (4 * wave + jt2) * 16 + jj;
                #pragma unroll
                for (int r = 0; r < 4; ++r) {
                    int b = 4 * q + r;
                    float ho = hcur[jt2 * 4 + r];
                    float rg = sigm(acc[jt2][r]);
                    float zg = sigm(acc[4 + jt2][r]);
                    float ng = tanh_f(xn4[jt2][r] + rg * (acc[8 + jt2][r] + bhn[jt2]));
                    float hn = ng + zg * (ho - ng);
                    hcur[jt2 * 4 + r] = hn;
                    short hb = f2bf(hn);
                    *(short*)((char*)sHl + b * 512 + ((2 * j) ^ ((b & 7) << 4))) = hb;
                    if (l < NL - 1) frdst[(size_t)ts * MB * HH + b * HH + j] = hb;
                    else            ydst[((size_t)g * MB + b) * HH + j] = hn;
                }
            }
            __syncthreads();   // h visible for next step
        }

        if (tid == 0) {
            if (l < NL - 1)
                __hip_atomic_store(seqf, t0 + CHUNK, __ATOMIC_RELEASE, __HIP_MEMORY_SCOPE_AGENT);
            if (l > 0)
                __hip_atomic_store(cseqf, t0 + CHUNK, __ATOMIC_RELEASE, __HIP_MEMORY_SCOPE_AGENT);
        }
    }

    // ---- final hidden states from registers ----
    #pragma unroll
    for (int jt2 = 0; jt2 < 4; ++jt2) {
        int j = (4 * wave + jt2) * 16 + jj;
        #pragma unroll
        for (int r = 0; r < 4; ++r)
            y[(size_t)SEQ * BB * HH + (size_t)l * BB * HH + ((size_t)g * MB + 4 * q + r) * HH + j] = hcur[jt2 * 4 + r];
    }
}

extern "C" void kernel_launch(void* const* d_in, const int* in_sizes, int n_in,
                              void* d_out, int out_size, void* d_ws, size_t ws_size,
                              hipStream_t stream) {
    (void)in_sizes; (void)n_in; (void)out_size; (void)ws_size;
    const float* x         = (const float*)d_in[0];
    const float* h0        = (const float*)d_in[1];
    const float* w_ih0     = (const float*)d_in[2];
    const float* w_ih_rest = (const float*)d_in[3];
    const float* w_hh      = (const float*)d_in[4];
    const float* b_ih      = (const float*)d_in[5];
    const float* b_hh      = (const float*)d_in[6];
    float* y = (float*)d_out;

    short* wstream = (short*)d_ws;
    short* fring   = wstream + STREAM_SH;
    float* xg      = (float*)((char*)d_ws + XG_OFF_B);
    int*   flags   = (int*)((char*)d_ws + FLAGS_OFF_B);

    (void)hipMemsetAsync(flags, 0, NFLAG_INTS * sizeof(int), stream);
    prep_frags<<<(TOT_F * 64) / 256, 256, 0, stream>>>(w_ih0, w_ih_rest, wstream);
    gru_persist<<<256, 256, 0, stream>>>(x, h0, w_hh, b_ih, b_hh, y,
                                         wstream, fring, xg, flags);
}

// Round 11
// 4672.564 us; speedup vs baseline: 1.9112x; 1.9112x over previous
//
#include <hip/hip_runtime.h>

#define SEQ 512
#define BB 64
#define IN_DIM 128
#define HH 256
#define NL 6
#define G3 768
#define CHUNK 8
#define NCH (SEQ/CHUNK)   // 64
#define FSTR 16           // ints per flag line

typedef short short8 __attribute__((ext_vector_type(8)));
typedef short short4v __attribute__((ext_vector_type(4)));
typedef float f32x4 __attribute__((ext_vector_type(4)));

// ws: fring[5][4][8][64][256] bf16 | xg[6][2][8][768][64] bf16 | flags
#define FR_SH ((size_t)5*4*CHUNK*BB*HH)          // 2,621,440 shorts
#define XG_SH ((size_t)NL*2*CHUNK*G3*BB)         // 4,718,592 shorts
#define FLAGS_OFF_B ((FR_SH + XG_SH)*2)
// flags: tickets[16] | recF[6][4]*FSTR | projF[6][16]*FSTR
#define NFLAG_INTS (16 + (24 + 96)*FSTR)

__device__ __forceinline__ short f2bf(float f) {
    unsigned u = __builtin_bit_cast(unsigned, f);
    u += 0x7fffu + ((u >> 16) & 1u);   // RNE
    return (short)(u >> 16);
}
__device__ __forceinline__ float b2f(short s) {
    unsigned u = ((unsigned)(unsigned short)s) << 16;
    return __builtin_bit_cast(float, u);
}
__device__ __forceinline__ float sigm(float v) { return __fdividef(1.f, 1.f + __expf(-v)); }
__device__ __forceinline__ float tanh_f(float v) { float e = __expf(2.f * v); return 1.f - __fdividef(2.f, e + 1.f); }

__device__ __forceinline__ short8 pack_row(const float* p) {
    float4 a = *(const float4*)p;
    float4 c = *(const float4*)(p + 4);
    short8 v;
    v[0] = f2bf(a.x); v[1] = f2bf(a.y); v[2] = f2bf(a.z); v[3] = f2bf(a.w);
    v[4] = f2bf(c.x); v[5] = f2bf(c.y); v[6] = f2bf(c.z); v[7] = f2bf(c.w);
    return v;
}

__global__ __launch_bounds__(512, 1) void gru_persist(
    const float* __restrict__ x, const float* __restrict__ h0,
    const float* __restrict__ w_ih0, const float* __restrict__ w_ih_rest,
    const float* __restrict__ w_hh, const float* __restrict__ b_ih,
    const float* __restrict__ b_hh, float* __restrict__ y,
    short* __restrict__ fring, short* __restrict__ xg, int* __restrict__ flags)
{
    extern __shared__ char smem[];   // 147456 B -> 1 WG/CU
    const int tid = threadIdx.x;
    const unsigned long long ddl = __builtin_amdgcn_s_memrealtime() + 800000000ull; // ~8s

    const int xcc = __builtin_amdgcn_s_getreg(20 | (31 << 11)) & 0xf;  // HW_REG_XCC_ID
    if (xcc >= NL) return;
    __shared__ int s_slot;
    if (tid == 0) s_slot = __hip_atomic_fetch_add(&flags[xcc], 1, __ATOMIC_RELAXED, __HIP_MEMORY_SCOPE_AGENT);
    __syncthreads();
    const int slot = s_slot;
    if (slot >= 20) return;

    const int l = xcc;
    const int lane = tid & 63;
    const int wave = tid >> 6;      // 0..7
    const int q = lane >> 4;
    const int jj = lane & 15;

    int* recF  = flags + 16;                 // (l*4+g)*FSTR
    int* projF = flags + 16 + 24 * FSTR;     // (l*16+p)*FSTR

    if (slot < 4) {
        // ================= REC CU: layer l, batch group g (16 batches) =================
        const int g = slot;
        char* sWn = smem;                       // 8 waves x 2 n-tiles x 8 kt x 1024 B
        char* sHB = smem + 131072;              // 2 x 16 x 512 B swizzled bf16 h

        const float* whh = w_hh + (size_t)l * G3 * HH;
        // r,z weight tiles in regs: i=0,1 -> r (jt2 0,1); i=2,3 -> z
        short8 Wreg[4][8];
        #pragma unroll
        for (int i = 0; i < 4; ++i) {
            int row = (i >> 1) * HH + 32 * wave + 16 * (i & 1) + jj;
            #pragma unroll
            for (int kt = 0; kt < 8; ++kt)
                Wreg[i][kt] = pack_row(whh + (size_t)row * HH + kt * 32 + q * 8);
        }
        // n tiles into LDS (frag-packed)
        #pragma unroll
        for (int i2 = 0; i2 < 2; ++i2) {
            int row = 512 + 32 * wave + 16 * i2 + jj;
            #pragma unroll
            for (int kt = 0; kt < 8; ++kt) {
                short8 v = pack_row(whh + (size_t)row * HH + kt * 32 + q * 8);
                *(short8*)(sWn + ((size_t)(wave * 2 + i2) * 8 + kt) * 1024 + lane * 16) = v;
            }
        }
        float bhr[2], bhz[2], bhn2[2];
        #pragma unroll
        for (int jt2 = 0; jt2 < 2; ++jt2) {
            int j = 32 * wave + 16 * jt2 + jj;
            bhr[jt2]  = b_hh[l * G3 + j];
            bhz[jt2]  = b_hh[l * G3 + 256 + j];
            bhn2[jt2] = b_hh[l * G3 + 512 + j];
        }
        float hcur[2][4];
        #pragma unroll
        for (int jt2 = 0; jt2 < 2; ++jt2) {
            int j = 32 * wave + 16 * jt2 + jj;
            #pragma unroll
            for (int r = 0; r < 4; ++r)
                hcur[jt2][r] = h0[((size_t)l * BB + 16 * g + 4 * q + r) * HH + j];
        }
        // sH[0] init (swizzled)
        for (int i = tid; i < 16 * 256; i += 512) {
            int b = i >> 8, j = i & 255;
            short hb = f2bf(h0[((size_t)l * BB + 16 * g + b) * HH + j]);
            *(short*)(sHB + b * 512 + ((2 * j) ^ ((b & 7) << 4))) = hb;
        }
        __syncthreads();

        for (int c = 0; c < NCH; ++c) {
            // chunk wait: xg ready (8 proj CUs) + fring slot free (8 proj CUs of l+1)
            if (wave == 0) {
                const int* pa = nullptr; int tgt = 0;
                if (lane < 8) { pa = &projF[(l * 16 + 2 * lane + (g >> 1)) * FSTR]; tgt = c + 1; }
                else if (lane < 16 && l < NL - 1) { pa = &projF[((l + 1) * 16 + 2 * (lane - 8) + (g >> 1)) * FSTR]; tgt = c - 3; }
                int it = 0;
                for (;;) {
                    bool ok = true;
                    if (pa) ok = __hip_atomic_load((int*)pa, __ATOMIC_RELAXED, __HIP_MEMORY_SCOPE_AGENT) >= tgt;
                    if (__ballot(ok) == ~0ull) break;
                    __builtin_amdgcn_s_sleep(1);
                    if (((++it) & 63) == 0 && __builtin_amdgcn_s_memrealtime() > ddl) break;
                }
                __builtin_amdgcn_fence(__ATOMIC_ACQUIRE, "agent");
            }
            __syncthreads();

            const short* xgc = xg + ((size_t)(l * 2 + (c & 1)) * CHUNK) * G3 * BB;
            short* frc = (l < NL - 1) ? fring + ((size_t)(l * 4 + (c & 3)) * CHUNK) * BB * HH : nullptr;

            for (int ts = 0; ts < CHUNK; ++ts) {
                const int t = c * CHUNK + ts;
                const int cur = t & 1, nxt = cur ^ 1;
                f32x4 acc[6] = {};   // 0,1=r  2,3=z  4,5=n
                #pragma unroll
                for (int kt = 0; kt < 8; ++kt) {
                    short8 af = *(const short8*)(sHB + cur * 8192 + (lane & 15) * 512
                                 + ((kt * 64 + q * 16) ^ ((lane & 7) << 4)));
                    acc[0] = __builtin_amdgcn_mfma_f32_16x16x32_bf16(af, Wreg[0][kt], acc[0], 0, 0, 0);
                    acc[1] = __builtin_amdgcn_mfma_f32_16x16x32_bf16(af, Wreg[1][kt], acc[1], 0, 0, 0);
                    acc[2] = __builtin_amdgcn_mfma_f32_16x16x32_bf16(af, Wreg[2][kt], acc[2], 0, 0, 0);
                    acc[3] = __builtin_amdgcn_mfma_f32_16x16x32_bf16(af, Wreg[3][kt], acc[3], 0, 0, 0);
                    short8 w4 = *(const short8*)(sWn + ((size_t)(wave * 2 + 0) * 8 + kt) * 1024 + lane * 16);
                    short8 w5 = *(const short8*)(sWn + ((size_t)(wave * 2 + 1) * 8 + kt) * 1024 + lane * 16);
                    acc[4] = __builtin_amdgcn_mfma_f32_16x16x32_bf16(af, w4, acc[4], 0, 0, 0);
                    acc[5] = __builtin_amdgcn_mfma_f32_16x16x32_bf16(af, w5, acc[5], 0, 0, 0);
                }
                const short* xgt = xgc + (size_t)ts * G3 * BB;
                float* ydst = y + (size_t)t * BB * HH;
                #pragma unroll
                for (int jt2 = 0; jt2 < 2; ++jt2) {
                    int j = 32 * wave + 16 * jt2 + jj;
                    short4v xr = *(const short4v*)(xgt + (size_t)j * BB + 16 * g + 4 * q);
                    short4v xz = *(const short4v*)(xgt + (size_t)(256 + j) * BB + 16 * g + 4 * q);
                    short4v xn = *(const short4v*)(xgt + (size_t)(512 + j) * BB + 16 * g + 4 * q);
                    #pragma unroll
                    for (int r = 0; r < 4; ++r) {
                        int b = 4 * q + r;
                        float rg = sigm(acc[jt2][r] + b2f(xr[r]) + bhr[jt2]);
                        float zg = sigm(acc[2 + jt2][r] + b2f(xz[r]) + bhz[jt2]);
                        float ng = tanh_f(b2f(xn[r]) + rg * (acc[4 + jt2][r] + bhn2[jt2]));
                        float hn = ng + zg * (hcur[jt2][r] - ng);
                        hcur[jt2][r] = hn;
                        short hb = f2bf(hn);
                        *(short*)(sHB + nxt * 8192 + b * 512 + ((2 * j) ^ ((b & 7) << 4))) = hb;
                        if (l < NL - 1) frc[((size_t)ts * BB + 16 * g + b) * HH + j] = hb;
                        else            ydst[((size_t)16 * g + b) * HH + j] = hn;
                    }
                }
                __syncthreads();
            }
            if (tid == 0)
                __hip_atomic_store(&recF[(l * 4 + g) * FSTR], c + 1, __ATOMIC_RELEASE, __HIP_MEMORY_SCOPE_AGENT);
        }
        // final hidden states
        #pragma unroll
        for (int jt2 = 0; jt2 < 2; ++jt2) {
            int j = 32 * wave + 16 * jt2 + jj;
            #pragma unroll
            for (int r = 0; r < 4; ++r)
                y[(size_t)SEQ * BB * HH + (size_t)l * BB * HH + ((size_t)16 * g + 4 * q + r) * HH + j] = hcur[jt2][r];
        }
    } else {
        // ================= PROJ CU: layer l, p = slot-4 (t_p = p>>1, bhalf = p&1) =================
        const int p = slot - 4;
        const int t_p = p >> 1;
        const int bh = p & 1;
        const int KIN = (l == 0) ? IN_DIM : HH;
        const int KTp = (l == 0) ? 4 : 8;
        char* sWp = smem;   // 8 waves x 2 lds-tiles x 8 kt x 1024

        const float* wih = (l == 0) ? w_ih0 : (w_ih_rest + (size_t)(l - 1) * G3 * HH);
        // wave owns nt = 6*wave + i (i 0..5): i 0..3 regs, i 4..5 LDS
        short8 Wp[4][8];
        #pragma unroll
        for (int i = 0; i < 4; ++i) {
            int row = (6 * wave + i) * 16 + jj;
            for (int kt = 0; kt < KTp; ++kt)
                Wp[i][kt] = pack_row(wih + (size_t)row * KIN + kt * 32 + q * 8);
        }
        #pragma unroll
        for (int i2 = 0; i2 < 2; ++i2) {
            int row = (6 * wave + 4 + i2) * 16 + jj;
            for (int kt = 0; kt < KTp; ++kt) {
                short8 v = pack_row(wih + (size_t)row * KIN + kt * 32 + q * 8);
                *(short8*)(sWp + ((size_t)(wave * 2 + i2) * 8 + kt) * 1024 + lane * 16) = v;
            }
        }
        float bias[6];
        #pragma unroll
        for (int i = 0; i < 6; ++i)
            bias[i] = b_ih[l * G3 + (6 * wave + i) * 16 + jj];
        __syncthreads();

        for (int c = 0; c < NCH; ++c) {
            if (wave == 0) {
                const int* pa = nullptr; int tgt = 0;
                if (lane < 2) { if (l > 0) { pa = &recF[((l - 1) * 4 + 2 * bh + lane) * FSTR]; tgt = c + 1; } }
                else if (lane < 4) { pa = &recF[(l * 4 + 2 * bh + (lane - 2)) * FSTR]; tgt = c - 1; }
                int it = 0;
                for (;;) {
                    bool ok = true;
                    if (pa) ok = __hip_atomic_load((int*)pa, __ATOMIC_RELAXED, __HIP_MEMORY_SCOPE_AGENT) >= tgt;
                    if (__ballot(ok) == ~0ull) break;
                    __builtin_amdgcn_s_sleep(1);
                    if (((++it) & 63) == 0 && __builtin_amdgcn_s_memrealtime() > ddl) break;
                }
                __builtin_amdgcn_fence(__ATOMIC_ACQUIRE, "agent");
            }
            __syncthreads();

            short* xgd = xg + ((size_t)(l * 2 + (c & 1)) * CHUNK + t_p) * G3 * BB;
            const short* frs = (l > 0)
                ? fring + ((size_t)((l - 1) * 4 + (c & 3)) * CHUNK + t_p) * BB * HH : nullptr;

            #pragma unroll
            for (int mt2 = 0; mt2 < 2; ++mt2) {
                const int bgl = 32 * bh + 16 * mt2 + (lane & 15);
                f32x4 acc[6] = {};
                for (int kt = 0; kt < KTp; ++kt) {
                    short8 af;
                    if (l == 0) {
                        const float* ap = x + ((size_t)(c * CHUNK + t_p) * BB + bgl) * IN_DIM + kt * 32 + q * 8;
                        af = pack_row(ap);
                    } else {
                        af = *(const short8*)(frs + (size_t)bgl * HH + kt * 32 + q * 8);
                    }
                    acc[0] = __builtin_amdgcn_mfma_f32_16x16x32_bf16(af, Wp[0][kt], acc[0], 0, 0, 0);
                    acc[1] = __builtin_amdgcn_mfma_f32_16x16x32_bf16(af, Wp[1][kt], acc[1], 0, 0, 0);
                    acc[2] = __builtin_amdgcn_mfma_f32_16x16x32_bf16(af, Wp[2][kt], acc[2], 0, 0, 0);
                    acc[3] = __builtin_amdgcn_mfma_f32_16x16x32_bf16(af, Wp[3][kt], acc[3], 0, 0, 0);
                    short8 w4 = *(const short8*)(sWp + ((size_t)(wave * 2 + 0) * 8 + kt) * 1024 + lane * 16);
                    short8 w5 = *(const short8*)(sWp + ((size_t)(wave * 2 + 1) * 8 + kt) * 1024 + lane * 16);
                    acc[4] = __builtin_amdgcn_mfma_f32_16x16x32_bf16(af, w4, acc[4], 0, 0, 0);
                    acc[5] = __builtin_amdgcn_mfma_f32_16x16x32_bf16(af, w5, acc[5], 0, 0, 0);
                }
                #pragma unroll
                for (int i = 0; i < 6; ++i) {
                    int j = (6 * wave + i) * 16 + jj;
                    short4v o;
                    o[0] = f2bf(acc[i][0] + bias[i]);
                    o[1] = f2bf(acc[i][1] + bias[i]);
                    o[2] = f2bf(acc[i][2] + bias[i]);
                    o[3] = f2bf(acc[i][3] + bias[i]);
                    *(short4v*)(xgd + (size_t)j * BB + 32 * bh + 16 * mt2 + 4 * q) = o;
                }
            }
            __syncthreads();   // drain xg stores before publish
            if (tid == 0)
                __hip_atomic_store(&projF[(l * 16 + p) * FSTR], c + 1, __ATOMIC_RELEASE, __HIP_MEMORY_SCOPE_AGENT);
        }
    }
}

extern "C" void kernel_launch(void* const* d_in, const int* in_sizes, int n_in,
                              void* d_out, int out_size, void* d_ws, size_t ws_size,
                              hipStream_t stream) {
    (void)in_sizes; (void)n_in; (void)out_size; (void)ws_size;
    const float* x         = (const float*)d_in[0];
    const float* h0        = (const float*)d_in[1];
    const float* w_ih0     = (const float*)d_in[2];
    const float* w_ih_rest = (const float*)d_in[3];
    const float* w_hh      = (const float*)d_in[4];
    const float* b_ih      = (const float*)d_in[5];
    const float* b_hh      = (const float*)d_in[6];
    float* y = (float*)d_out;

    short* fring = (short*)d_ws;
    short* xgb   = fring + FR_SH;
    int*   flags = (int*)((char*)d_ws + FLAGS_OFF_B);

    (void)hipMemsetAsync(flags, 0, NFLAG_INTS * sizeof(int), stream);
    gru_persist<<<256, 512, 147456, stream>>>(
        x, h0, w_ih0, w_ih_rest, w_hh, b_ih, b_hh, y, fring, xgb, flags);
}

// Round 12
// 4094.822 us; speedup vs baseline: 2.1808x; 1.1411x over previous
//
#include <hip/hip_runtime.h>

#define SEQ 512
#define BB 64
#define IN_DIM 128
#define HH 256
#define NL 6
#define G3 768
#define CHUNK 8
#define NCH (SEQ/CHUNK)   // 64
#define FSTR 16           // ints per flag line

typedef short short8 __attribute__((ext_vector_type(8)));
typedef short short4v __attribute__((ext_vector_type(4)));
typedef float f32x4 __attribute__((ext_vector_type(4)));

// ws: fring[5][4][8][64][256] bf16 | xg[6][2][8][4][768][16] bf16 | flags
#define FR_SH ((size_t)5*4*CHUNK*BB*HH)
#define XG_SH ((size_t)NL*2*CHUNK*4*G3*16)
#define FLAGS_OFF_B ((FR_SH + XG_SH)*2)
#define NFLAG_INTS (16 + (24 + 96)*FSTR)
#define XGI(L,CS,TS,GI) (((((size_t)(L)*2+(CS))*CHUNK+(TS))*4+(GI))*((size_t)G3*16))

__device__ __forceinline__ short f2bf(float f) {
    unsigned u = __builtin_bit_cast(unsigned, f);
    u += 0x7fffu + ((u >> 16) & 1u);   // RNE
    return (short)(u >> 16);
}
__device__ __forceinline__ float b2f(short s) {
    unsigned u = ((unsigned)(unsigned short)s) << 16;
    return __builtin_bit_cast(float, u);
}
__device__ __forceinline__ float sigm(float v) { return __fdividef(1.f, 1.f + __expf(-v)); }
__device__ __forceinline__ float tanh_f(float v) { float e = __expf(2.f * v); return 1.f - __fdividef(2.f, e + 1.f); }

__device__ __forceinline__ short8 pack_row(const float* p) {
    float4 a = *(const float4*)p;
    float4 c = *(const float4*)(p + 4);
    short8 v;
    v[0] = f2bf(a.x); v[1] = f2bf(a.y); v[2] = f2bf(a.z); v[3] = f2bf(a.w);
    v[4] = f2bf(c.x); v[5] = f2bf(c.y); v[6] = f2bf(c.z); v[7] = f2bf(c.w);
    return v;
}

struct XgRegs { short4v r0, r1, z0, z1, n0, n1; };
// async sc0 (L1-bypass) loads; caller waits vmcnt(0) before use
__device__ __forceinline__ XgRegs ld_xg(const short* pR, const short* pZ, const short* pN) {
    XgRegs o;
    asm volatile(
        "global_load_dwordx2 %0, %6, off sc0\n\t"
        "global_load_dwordx2 %1, %6, off offset:512 sc0\n\t"
        "global_load_dwordx2 %2, %7, off sc0\n\t"
        "global_load_dwordx2 %3, %7, off offset:512 sc0\n\t"
        "global_load_dwordx2 %4, %8, off sc0\n\t"
        "global_load_dwordx2 %5, %8, off offset:512 sc0"
        : "=&v"(o.r0), "=&v"(o.r1), "=&v"(o.z0), "=&v"(o.z1), "=&v"(o.n0), "=&v"(o.n1)
        : "v"(pR), "v"(pZ), "v"(pN) : "memory");
    return o;
}

__global__ __launch_bounds__(512, 1) void gru_persist(
    const float* __restrict__ x, const float* __restrict__ h0,
    const float* __restrict__ w_ih0, const float* __restrict__ w_ih_rest,
    const float* __restrict__ w_hh, const float* __restrict__ b_ih,
    const float* __restrict__ b_hh, float* __restrict__ y,
    short* __restrict__ fring, short* __restrict__ xg, int* __restrict__ flags)
{
    extern __shared__ char smem[];   // 147456 B -> 1 WG/CU
    const int tid = threadIdx.x;
    const unsigned long long ddl = __builtin_amdgcn_s_memrealtime() + 800000000ull; // ~8s

    const int xcc = __builtin_amdgcn_s_getreg(20 | (31 << 11)) & 0xf;  // HW_REG_XCC_ID
    if (xcc >= NL) return;
    __shared__ int s_slot;
    if (tid == 0) s_slot = __hip_atomic_fetch_add(&flags[xcc], 1, __ATOMIC_RELAXED, __HIP_MEMORY_SCOPE_AGENT);
    __syncthreads();
    const int slot = s_slot;
    if (slot >= 20) return;

    const int l = xcc;
    const int lane = tid & 63;
    const int wave = tid >> 6;      // 0..7
    const int q = lane >> 4;
    const int jj = lane & 15;

    int* recF  = flags + 16;                 // (l*4+g)*FSTR
    int* projF = flags + 16 + 24 * FSTR;     // (l*16+p)*FSTR

    if (slot < 4) {
        // ================= REC CU: layer l, batch group g =================
        const int g = slot;
        char* sWn = smem;                       // 8 waves x 2 n-tiles x 8 kt x 1024
        char* sHB = smem + 131072;              // 2 x 16 x 512 B swizzled bf16 h

        const float* whh = w_hh + (size_t)l * G3 * HH;
        short8 Wreg[4][8];
        #pragma unroll
        for (int i = 0; i < 4; ++i) {
            int row = (i >> 1) * HH + 32 * wave + 16 * (i & 1) + jj;
            #pragma unroll
            for (int kt = 0; kt < 8; ++kt)
                Wreg[i][kt] = pack_row(whh + (size_t)row * HH + kt * 32 + q * 8);
        }
        #pragma unroll
        for (int i2 = 0; i2 < 2; ++i2) {
            int row = 512 + 32 * wave + 16 * i2 + jj;
            #pragma unroll
            for (int kt = 0; kt < 8; ++kt) {
                short8 v = pack_row(whh + (size_t)row * HH + kt * 32 + q * 8);
                *(short8*)(sWn + ((size_t)(wave * 2 + i2) * 8 + kt) * 1024 + lane * 16) = v;
            }
        }
        float bhr[2], bhz[2], bhn2[2];
        #pragma unroll
        for (int jt2 = 0; jt2 < 2; ++jt2) {
            int j = 32 * wave + 16 * jt2 + jj;
            bhr[jt2]  = b_hh[l * G3 + j];
            bhz[jt2]  = b_hh[l * G3 + 256 + j];
            bhn2[jt2] = b_hh[l * G3 + 512 + j];
        }
        float hcur[2][4];
        #pragma unroll
        for (int jt2 = 0; jt2 < 2; ++jt2) {
            int j = 32 * wave + 16 * jt2 + jj;
            #pragma unroll
            for (int r = 0; r < 4; ++r)
                hcur[jt2][r] = h0[((size_t)l * BB + 16 * g + 4 * q + r) * HH + j];
        }
        for (int i = tid; i < 16 * 256; i += 512) {
            int b = i >> 8, j = i & 255;
            short hb = f2bf(h0[((size_t)l * BB + 16 * g + b) * HH + j]);
            *(short*)(sHB + b * 512 + ((2 * j) ^ ((b & 7) << 4))) = hb;
        }
        __syncthreads();

        const int cb = tid >> 5;                 // copy mapping: batch, j-block
        const int cj0 = (tid & 31) * 8;

        for (int c = 0; c < NCH; ++c) {
            // chunk wait (no acquire fence needed: xg via sc0; other wait is slot-free only)
            if (wave == 0) {
                const int* pa = nullptr; int tgt = 0;
                if (lane < 8) { pa = &projF[(l * 16 + 2 * lane + (g >> 1)) * FSTR]; tgt = c + 1; }
                else if (lane < 16 && l < NL - 1) { pa = &projF[((l + 1) * 16 + 2 * (lane - 8) + (g >> 1)) * FSTR]; tgt = c - 3; }
                int it = 0;
                for (;;) {
                    bool ok = true;
                    if (pa) ok = __hip_atomic_load((int*)pa, __ATOMIC_RELAXED, __HIP_MEMORY_SCOPE_AGENT) >= tgt;
                    if (__ballot(ok) == ~0ull) break;
                    __builtin_amdgcn_s_sleep(1);
                    if (((++it) & 63) == 0 && __builtin_amdgcn_s_memrealtime() > ddl) break;
                }
            }
            __syncthreads();

            short* frc = (l < NL - 1) ? fring + ((size_t)(l * 4 + (c & 3)) * CHUNK) * BB * HH : nullptr;

            for (int ts = 0; ts < CHUNK; ++ts) {
                const int t = c * CHUNK + ts;
                const int cur = t & 1, nxt = cur ^ 1;

                // issue xg loads (sc0, async; arrive under MFMA)
                const short* xgts = xg + XGI(l, c & 1, ts, g);
                const short* pR = xgts + (32 * wave + jj) * 16 + 4 * q;
                XgRegs xr = ld_xg(pR, pR + 256 * 16, pR + 512 * 16);

                f32x4 acc[6] = {};   // 0,1=r  2,3=z  4,5=n
                #pragma unroll
                for (int kt = 0; kt < 8; ++kt) {
                    short8 af = *(const short8*)(sHB + cur * 8192 + (lane & 15) * 512
                                 + ((kt * 64 + q * 16) ^ ((lane & 7) << 4)));
                    acc[0] = __builtin_amdgcn_mfma_f32_16x16x32_bf16(af, Wreg[0][kt], acc[0], 0, 0, 0);
                    acc[1] = __builtin_amdgcn_mfma_f32_16x16x32_bf16(af, Wreg[1][kt], acc[1], 0, 0, 0);
                    acc[2] = __builtin_amdgcn_mfma_f32_16x16x32_bf16(af, Wreg[2][kt], acc[2], 0, 0, 0);
                    acc[3] = __builtin_amdgcn_mfma_f32_16x16x32_bf16(af, Wreg[3][kt], acc[3], 0, 0, 0);
                    short8 w4 = *(const short8*)(sWn + ((size_t)(wave * 2 + 0) * 8 + kt) * 1024 + lane * 16);
                    short8 w5 = *(const short8*)(sWn + ((size_t)(wave * 2 + 1) * 8 + kt) * 1024 + lane * 16);
                    acc[4] = __builtin_amdgcn_mfma_f32_16x16x32_bf16(af, w4, acc[4], 0, 0, 0);
                    acc[5] = __builtin_amdgcn_mfma_f32_16x16x32_bf16(af, w5, acc[5], 0, 0, 0);
                }
                asm volatile("s_waitcnt vmcnt(0)" ::: "memory");   // xg arrived (+ prior copies drained)

                #pragma unroll
                for (int jt2 = 0; jt2 < 2; ++jt2) {
                    int j = 32 * wave + 16 * jt2 + jj;
                    short4v xrv = jt2 ? xr.r1 : xr.r0;
                    short4v xzv = jt2 ? xr.z1 : xr.z0;
                    short4v xnv = jt2 ? xr.n1 : xr.n0;
                    #pragma unroll
                    for (int r = 0; r < 4; ++r) {
                        int b = 4 * q + r;
                        float rg = sigm(acc[jt2][r] + b2f(xrv[r]) + bhr[jt2]);
                        float zg = sigm(acc[2 + jt2][r] + b2f(xzv[r]) + bhz[jt2]);
                        float ng = tanh_f(b2f(xnv[r]) + rg * (acc[4 + jt2][r] + bhn2[jt2]));
                        float hn = ng + zg * (hcur[jt2][r] - ng);
                        hcur[jt2][r] = hn;
                        *(short*)(sHB + nxt * 8192 + b * 512 + ((2 * j) ^ ((b & 7) << 4))) = f2bf(hn);
                    }
                }
                __syncthreads();   // sHB[nxt] complete

                // coalesced copy of h(t): one short8 LDS read + wide store per thread
                short8 hv = *(const short8*)(sHB + nxt * 8192 + cb * 512 + ((2 * cj0) ^ ((cb & 7) << 4)));
                if (l < NL - 1) {
                    *(short8*)(frc + ((size_t)ts * BB + 16 * g + cb) * HH + cj0) = hv;
                } else {
                    float4 f0, f1;
                    f0.x = b2f(hv[0]); f0.y = b2f(hv[1]); f0.z = b2f(hv[2]); f0.w = b2f(hv[3]);
                    f1.x = b2f(hv[4]); f1.y = b2f(hv[5]); f1.z = b2f(hv[6]); f1.w = b2f(hv[7]);
                    float* yd = y + ((size_t)t * BB + 16 * g + cb) * HH + cj0;
                    *(float4*)yd = f0;
                    *(float4*)(yd + 4) = f1;
                }
            }
            __syncthreads();       // drain copy stores before publish
            if (tid == 0)
                __hip_atomic_store(&recF[(l * 4 + g) * FSTR], c + 1, __ATOMIC_RELEASE, __HIP_MEMORY_SCOPE_AGENT);
        }
        // final hidden states (fp32 from regs)
        #pragma unroll
        for (int jt2 = 0; jt2 < 2; ++jt2) {
            int j = 32 * wave + 16 * jt2 + jj;
            #pragma unroll
            for (int r = 0; r < 4; ++r)
                y[(size_t)SEQ * BB * HH + (size_t)l * BB * HH + ((size_t)16 * g + 4 * q + r) * HH + j] = hcur[jt2][r];
        }
    } else {
        // ================= PROJ CU: layer l, p = slot-4 =================
        const int p = slot - 4;
        const int t_p = p >> 1;
        const int bh = p & 1;
        const int KIN = (l == 0) ? IN_DIM : HH;
        const int KTp = (l == 0) ? 4 : 8;
        char* sWp = smem;

        const float* wih = (l == 0) ? w_ih0 : (w_ih_rest + (size_t)(l - 1) * G3 * HH);
        short8 Wp[4][8];
        #pragma unroll
        for (int i = 0; i < 4; ++i) {
            int row = (6 * wave + i) * 16 + jj;
            for (int kt = 0; kt < KTp; ++kt)
                Wp[i][kt] = pack_row(wih + (size_t)row * KIN + kt * 32 + q * 8);
        }
        #pragma unroll
        for (int i2 = 0; i2 < 2; ++i2) {
            int row = (6 * wave + 4 + i2) * 16 + jj;
            for (int kt = 0; kt < KTp; ++kt) {
                short8 v = pack_row(wih + (size_t)row * KIN + kt * 32 + q * 8);
                *(short8*)(sWp + ((size_t)(wave * 2 + i2) * 8 + kt) * 1024 + lane * 16) = v;
            }
        }
        float bias[6];
        #pragma unroll
        for (int i = 0; i < 6; ++i)
            bias[i] = b_ih[l * G3 + (6 * wave + i) * 16 + jj];
        __syncthreads();

        for (int c = 0; c < NCH; ++c) {
            if (wave == 0) {
                const int* pa = nullptr; int tgt = 0;
                if (lane < 2) { if (l > 0) { pa = &recF[((l - 1) * 4 + 2 * bh + lane) * FSTR]; tgt = c + 1; } }
                else if (lane < 4) { pa = &recF[(l * 4 + 2 * bh + (lane - 2)) * FSTR]; tgt = c - 1; }
                int it = 0;
                for (;;) {
                    bool ok = true;
                    if (pa) ok = __hip_atomic_load((int*)pa, __ATOMIC_RELAXED, __HIP_MEMORY_SCOPE_AGENT) >= tgt;
                    if (__ballot(ok) == ~0ull) break;
                    __builtin_amdgcn_s_sleep(1);
                    if (((++it) & 63) == 0 && __builtin_amdgcn_s_memrealtime() > ddl) break;
                }
                if (l > 0) __builtin_amdgcn_fence(__ATOMIC_ACQUIRE, "agent");
            }
            __syncthreads();

            const short* frs = (l > 0)
                ? fring + ((size_t)((l - 1) * 4 + (c & 3)) * CHUNK + t_p) * BB * HH : nullptr;

            #pragma unroll
            for (int mt2 = 0; mt2 < 2; ++mt2) {
                const int bgl = 32 * bh + 16 * mt2 + (lane & 15);
                // batch-preload all A fragments (compiler overlaps the loads)
                short8 afv[8];
                for (int kt = 0; kt < KTp; ++kt) {
                    if (l == 0)
                        afv[kt] = pack_row(x + ((size_t)(c * CHUNK + t_p) * BB + bgl) * IN_DIM + kt * 32 + q * 8);
                    else
                        afv[kt] = *(const short8*)(frs + (size_t)bgl * HH + kt * 32 + q * 8);
                }
                f32x4 acc[6] = {};
                for (int kt = 0; kt < KTp; ++kt) {
                    short8 af = afv[kt];
                    acc[0] = __builtin_amdgcn_mfma_f32_16x16x32_bf16(af, Wp[0][kt], acc[0], 0, 0, 0);
                    acc[1] = __builtin_amdgcn_mfma_f32_16x16x32_bf16(af, Wp[1][kt], acc[1], 0, 0, 0);
                    acc[2] = __builtin_amdgcn_mfma_f32_16x16x32_bf16(af, Wp[2][kt], acc[2], 0, 0, 0);
                    acc[3] = __builtin_amdgcn_mfma_f32_16x16x32_bf16(af, Wp[3][kt], acc[3], 0, 0, 0);
                    short8 w4 = *(const short8*)(sWp + ((size_t)(wave * 2 + 0) * 8 + kt) * 1024 + lane * 16);
                    short8 w5 = *(const short8*)(sWp + ((size_t)(wave * 2 + 1) * 8 + kt) * 1024 + lane * 16);
                    acc[4] = __builtin_amdgcn_mfma_f32_16x16x32_bf16(af, w4, acc[4], 0, 0, 0);
                    acc[5] = __builtin_amdgcn_mfma_f32_16x16x32_bf16(af, w5, acc[5], 0, 0, 0);
                }
                short* xgd = xg + XGI(l, c & 1, t_p, 2 * bh + mt2);
                #pragma unroll
                for (int i = 0; i < 6; ++i) {
                    int r = (6 * wave + i) * 16 + jj;
                    short4v o;
                    o[0] = f2bf(acc[i][0] + bias[i]);
                    o[1] = f2bf(acc[i][1] + bias[i]);
                    o[2] = f2bf(acc[i][2] + bias[i]);
                    o[3] = f2bf(acc[i][3] + bias[i]);
                    *(short4v*)(xgd + (size_t)r * 16 + 4 * q) = o;   // plain store -> shared L2
                }
            }
            __syncthreads();   // drain xg stores before publish
            if (tid == 0)
                __hip_atomic_store(&projF[(l * 16 + p) * FSTR], c + 1, __ATOMIC_RELEASE, __HIP_MEMORY_SCOPE_AGENT);
        }
    }
}

extern "C" void kernel_launch(void* const* d_in, const int* in_sizes, int n_in,
                              void* d_out, int out_size, void* d_ws, size_t ws_size,
                              hipStream_t stream) {
    (void)in_sizes; (void)n_in; (void)out_size; (void)ws_size;
    const float* x         = (const float*)d_in[0];
    const float* h0        = (const float*)d_in[1];
    const float* w_ih0     = (const float*)d_in[2];
    const float* w_ih_rest = (const float*)d_in[3];
    const float* w_hh      = (const float*)d_in[4];
    const float* b_ih      = (const float*)d_in[5];
    const float* b_hh      = (const float*)d_in[6];
    float* y = (float*)d_out;

    short* fring = (short*)d_ws;
    short* xgb   = fring + FR_SH;
    int*   flags = (int*)((char*)d_ws + FLAGS_OFF_B);

    (void)hipMemsetAsync(flags, 0, NFLAG_INTS * sizeof(int), stream);
    gru_persist<<<256, 512, 147456, stream>>>(
        x, h0, w_ih0, w_ih_rest, w_hh, b_ih, b_hh, y, fring, xgb, flags);
}